// Round 5
// baseline (2674.731 us; speedup 1.0000x reference)
//
#include <hip/hip_runtime.h>
#include <hip/hip_bf16.h>

#define DE 128
#define SB 256          // scan chunk
#define NPB 8           // nodes per block in fused kernel (8 * 32 threads = 256)
#define PF 8            // gather pipeline depth (rows in flight per group)

typedef float f4 __attribute__((ext_vector_type(4)));

// ---------------------------------------------------------------------------
// CSR build: histogram over all 3 relations in one launch
// ---------------------------------------------------------------------------
__global__ void count_all(const int* __restrict__ d0, const int* __restrict__ d1,
                          const int* __restrict__ d2, int* __restrict__ cnt,
                          int N, int n0, int n1, int n2) {
    int i = blockIdx.x * blockDim.x + threadIdx.x;
    int total = n0 + n1 + n2;
    if (i >= total) return;
    int r, j;
    if (i < n0)            { r = 0; j = i; }
    else if (i < n0 + n1)  { r = 1; j = i - n0; }
    else                   { r = 2; j = i - n0 - n1; }
    const int* d = (r == 0) ? d0 : (r == 1) ? d1 : d2;
    atomicAdd(&cnt[(size_t)r * N + d[j]], 1);
}

// block-local exclusive scan of cnt -> off, block totals -> bs
__global__ void scan1(const int* __restrict__ cnt, int* __restrict__ off,
                      int* __restrict__ bs, int N, int nchunks) {
    int r = blockIdx.y, c = blockIdx.x, tid = threadIdx.x;
    int i = c * SB + tid;
    __shared__ int s[SB];
    int v = (i < N) ? cnt[(size_t)r * N + i] : 0;
    s[tid] = v; __syncthreads();
    for (int d = 1; d < SB; d <<= 1) {
        int tv = (tid >= d) ? s[tid - d] : 0;
        __syncthreads();
        s[tid] += tv;
        __syncthreads();
    }
    if (i < N) off[(size_t)r * N + i] = s[tid] - v;     // exclusive within chunk
    if (tid == SB - 1) bs[r * nchunks + c] = s[tid];
}

// scan the chunk totals (nchunks <= 512)
__global__ void scan2(int* __restrict__ bs, int nchunks) {
    int r = blockIdx.x, tid = threadIdx.x;
    __shared__ int s[512];
    int v = (tid < nchunks) ? bs[r * nchunks + tid] : 0;
    s[tid] = v; __syncthreads();
    for (int d = 1; d < 512; d <<= 1) {
        int tv = (tid >= d) ? s[tid - d] : 0;
        __syncthreads();
        s[tid] += tv;
        __syncthreads();
    }
    if (tid < nchunks) bs[r * nchunks + tid] = s[tid] - v;  // exclusive
}

// add chunk offsets, produce final exclusive offsets + cursor copy
__global__ void scan3(int* __restrict__ off, const int* __restrict__ bs,
                      int* __restrict__ cur, int N, int nchunks) {
    int r = blockIdx.y;
    int i = blockIdx.x * SB + threadIdx.x;
    if (i < N) {
        int v = off[(size_t)r * N + i] + bs[r * nchunks + blockIdx.x];
        off[(size_t)r * N + i] = v;
        cur[(size_t)r * N + i] = v;
    }
}

// bucket-fill edge ids sorted by destination, all 3 relations in one launch
__global__ void fill_all(const int* __restrict__ d0, const int* __restrict__ d1,
                         const int* __restrict__ d2, int* __restrict__ cur,
                         int* __restrict__ eid, int N, int n0, int n1, int n2) {
    int i = blockIdx.x * blockDim.x + threadIdx.x;
    int total = n0 + n1 + n2;
    if (i >= total) return;
    int r, j, base;
    if (i < n0)            { r = 0; j = i;            base = 0; }
    else if (i < n0 + n1)  { r = 1; j = i - n0;       base = n0; }
    else                   { r = 2; j = i - n0 - n1;  base = n0 + n1; }
    const int* d = (r == 0) ? d0 : (r == 1) ? d1 : d2;
    int node = d[j];
    int p = atomicAdd(&cur[(size_t)r * N + node], 1);
    eid[base + p] = j;
}

// ---------------------------------------------------------------------------
// Fused: gather-mean (CSR) + tanh-gate attention + projection.
// 256 threads = 8 nodes x 32 threads, wave-local groups (no __syncthreads).
// Gather uses an 8-deep rolling software pipeline: buf[i] always holds an
// in-flight row; consume-oldest + reissue keeps 8 loads outstanding.
// ---------------------------------------------------------------------------
__global__ __launch_bounds__(256) void node_fused(
        const float* __restrict__ E0, const float* __restrict__ E1,
        const float* __restrict__ E2,
        const int* __restrict__ eid,   // [sum nE], per-relation bases
        const int* __restrict__ off,   // [3,N]
        const int* __restrict__ cnt,   // [3,N]
        const float* __restrict__ W1, const float* __restrict__ W2,
        const float* __restrict__ W3,
        float* __restrict__ out, int N, int base1, int base2) {
    const int ln = threadIdx.x >> 5;     // local node 0..7
    const int t  = threadIdx.x & 31;     // lane in group
    const int node = blockIdx.x * NPB + ln;
    if (node >= N) return;

    __shared__ float Ysh[NPB][3][DE];    // 12 KB
    __shared__ float OYsh[NPB][DE];      // 4 KB

    const float* Es[3] = { E0, E1, E2 };
    const int ebase[3] = { 0, base1, base2 };

    // ---- gather + mean: thread t owns cols 4t..4t+3 (f4 per edge row)
    #pragma unroll
    for (int r = 0; r < 3; ++r) {
        int start = off[(size_t)r * N + node];
        int deg   = cnt[(size_t)r * N + node];
        const int* el = eid + ebase[r] + start;
        const float* E = Es[r];
        f4 acc = {0.f, 0.f, 0.f, 0.f};
        f4 buf[PF];

        // prologue: issue up to PF row loads
        #pragma unroll
        for (int i = 0; i < PF; ++i) {
            if (i < deg) {
                int e = el[i];
                buf[i] = __builtin_nontemporal_load(
                    reinterpret_cast<const f4*>(E + (size_t)e * DE + t * 4));
            }
        }

        int kb = 0;
        for (; kb + PF < deg; kb += PF) {
            // issue next batch's eid loads early (L2 latency hidden under rows)
            int enext[PF];
            #pragma unroll
            for (int i = 0; i < PF; ++i) {
                int kn = kb + PF + i;
                enext[i] = (kn < deg) ? el[kn] : 0;
            }
            // consume current rows; immediately reissue into same slot
            #pragma unroll
            for (int i = 0; i < PF; ++i) {
                f4 v = buf[i];
                int kn = kb + PF + i;
                if (kn < deg) {
                    buf[i] = __builtin_nontemporal_load(
                        reinterpret_cast<const f4*>(E + (size_t)enext[i] * DE + t * 4));
                }
                acc += v;
            }
        }
        // tail: consume remaining loaded rows
        #pragma unroll
        for (int i = 0; i < PF; ++i) {
            if (kb + i < deg) acc += buf[i];
        }

        float inv = 1.0f / fmaxf((float)deg, 1.0f);
        acc *= inv;
        *reinterpret_cast<f4*>(&Ysh[ln][r][t * 4]) = acc;
    }

    // ---- z[r][j] = sum_d Y[r][d] * W1[d][t + 32j]   (register-blocked)
    float z[3][4] = {{0,0,0,0},{0,0,0,0},{0,0,0,0}};
    for (int d0 = 0; d0 < DE; d0 += 4) {
        f4 y0 = *reinterpret_cast<const f4*>(&Ysh[ln][0][d0]);
        f4 y1 = *reinterpret_cast<const f4*>(&Ysh[ln][1][d0]);
        f4 y2 = *reinterpret_cast<const f4*>(&Ysh[ln][2][d0]);
        #pragma unroll
        for (int dd = 0; dd < 4; ++dd) {
            int d = d0 + dd;
            const float* wrow = W1 + (size_t)d * DE + t;
            float w0 = wrow[0], w1 = wrow[32], w2 = wrow[64], w3 = wrow[96];
            float a0 = y0[dd], a1 = y1[dd], a2 = y2[dd];
            z[0][0] = fmaf(a0, w0, z[0][0]); z[0][1] = fmaf(a0, w1, z[0][1]);
            z[0][2] = fmaf(a0, w2, z[0][2]); z[0][3] = fmaf(a0, w3, z[0][3]);
            z[1][0] = fmaf(a1, w0, z[1][0]); z[1][1] = fmaf(a1, w1, z[1][1]);
            z[1][2] = fmaf(a1, w2, z[1][2]); z[1][3] = fmaf(a1, w3, z[1][3]);
            z[2][0] = fmaf(a2, w0, z[2][0]); z[2][1] = fmaf(a2, w1, z[2][1]);
            z[2][2] = fmaf(a2, w2, z[2][2]); z[2][3] = fmaf(a2, w3, z[2][3]);
        }
    }

    // ---- scores: e_r = sum_o tanh(z_r[o]) * W2[o]; reduce over 32 lanes
    float s0 = 0.f, s1 = 0.f, s2 = 0.f;
    #pragma unroll
    for (int j = 0; j < 4; ++j) {
        float w2v = W2[t + j * 32];
        s0 = fmaf(tanhf(z[0][j]), w2v, s0);
        s1 = fmaf(tanhf(z[1][j]), w2v, s1);
        s2 = fmaf(tanhf(z[2][j]), w2v, s2);
    }
    #pragma unroll
    for (int m = 16; m >= 1; m >>= 1) {
        s0 += __shfl_xor(s0, m);
        s1 += __shfl_xor(s1, m);
        s2 += __shfl_xor(s2, m);
    }
    float mx = fmaxf(s0, fmaxf(s1, s2));
    float x0 = __expf(s0 - mx), x1 = __expf(s1 - mx), x2 = __expf(s2 - mx);
    float inv = 1.0f / (x0 + x1 + x2);
    float a0 = x0 * inv, a1 = x1 * inv, a2 = x2 * inv;

    // ---- OY = sum_r a_r * Y_r  -> LDS
    #pragma unroll
    for (int j = 0; j < 4; ++j) {
        int o = t + j * 32;
        OYsh[ln][o] = a0 * Ysh[ln][0][o] + a1 * Ysh[ln][1][o] + a2 * Ysh[ln][2][o];
    }

    // ---- out = OY @ W3 (register-blocked, 4 cols/thread)
    float o4[4] = {0, 0, 0, 0};
    for (int d0 = 0; d0 < DE; d0 += 4) {
        f4 oy = *reinterpret_cast<const f4*>(&OYsh[ln][d0]);
        #pragma unroll
        for (int dd = 0; dd < 4; ++dd) {
            int d = d0 + dd;
            const float* wrow = W3 + (size_t)d * DE + t;
            o4[0] = fmaf(oy[dd], wrow[0],  o4[0]);
            o4[1] = fmaf(oy[dd], wrow[32], o4[1]);
            o4[2] = fmaf(oy[dd], wrow[64], o4[2]);
            o4[3] = fmaf(oy[dd], wrow[96], o4[3]);
        }
    }
    #pragma unroll
    for (int j = 0; j < 4; ++j) out[(size_t)node * DE + t + j * 32] = o4[j];
}

// ---------------------------------------------------------------------------
// launch
// ---------------------------------------------------------------------------
extern "C" void kernel_launch(void* const* d_in, const int* in_sizes, int n_in,
                              void* d_out, int out_size, void* d_ws, size_t ws_size,
                              hipStream_t stream) {
    const float* E_C = (const float*)d_in[0];
    const float* E_D = (const float*)d_in[1];
    const float* E_M = (const float*)d_in[2];
    const int* dst_C = (const int*)d_in[3];
    const int* dst_D = (const int*)d_in[4];
    const int* dst_M = (const int*)d_in[5];
    const float* W1 = (const float*)d_in[7];
    const float* W2 = (const float*)d_in[8];
    const float* W3 = (const float*)d_in[9];
    float* out = (float*)d_out;

    const int N = out_size / DE;                     // 100000
    const int nE[3] = { in_sizes[3], in_sizes[4], in_sizes[5] };
    const int NEtot = nE[0] + nE[1] + nE[2];
    const int nchunks = (N + SB - 1) / SB;           // 391 for N=100000

    // workspace (ints): eid[NEtot] | cnt[3N] | off[3N] | cur[3N] | bs[3*nchunks]
    int* eid = (int*)d_ws;
    int* cnt = eid + NEtot;
    int* off = cnt + 3 * (size_t)N;
    int* cur = off + 3 * (size_t)N;
    int* bs  = cur + 3 * (size_t)N;

    (void)hipMemsetAsync(cnt, 0, 3 * (size_t)N * sizeof(int), stream);

    {
        int blocks = (NEtot + 255) / 256;
        count_all<<<blocks, 256, 0, stream>>>(dst_C, dst_D, dst_M, cnt,
                                              N, nE[0], nE[1], nE[2]);
    }

    dim3 g1(nchunks, 3);
    scan1<<<g1, SB, 0, stream>>>(cnt, off, bs, N, nchunks);
    scan2<<<3, 512, 0, stream>>>(bs, nchunks);
    scan3<<<g1, SB, 0, stream>>>(off, bs, cur, N, nchunks);

    {
        int blocks = (NEtot + 255) / 256;
        fill_all<<<blocks, 256, 0, stream>>>(dst_C, dst_D, dst_M, cur, eid,
                                             N, nE[0], nE[1], nE[2]);
    }

    int nblocks = (N + NPB - 1) / NPB;
    node_fused<<<nblocks, 256, 0, stream>>>(
        E_C, E_D, E_M, eid, off, cnt, W1, W2, W3, out,
        N, nE[0], nE[0] + nE[1]);
}

// Round 6
// 993.085 us; speedup vs baseline: 2.6934x; 2.6934x over previous
//
#include <hip/hip_runtime.h>
#include <hip/hip_bf16.h>

#define DE 128
#define SB 256          // scan chunk
#define NPB 8           // nodes per block in fused kernel (8 * 32 threads = 256)

typedef float f4 __attribute__((ext_vector_type(4)));

// ---------------------------------------------------------------------------
// CSR build: histogram over all 3 relations in one launch
// ---------------------------------------------------------------------------
__global__ void count_all(const int* __restrict__ d0, const int* __restrict__ d1,
                          const int* __restrict__ d2, int* __restrict__ cnt,
                          int N, int n0, int n1, int n2) {
    int i = blockIdx.x * blockDim.x + threadIdx.x;
    int total = n0 + n1 + n2;
    if (i >= total) return;
    int r, j;
    if (i < n0)            { r = 0; j = i; }
    else if (i < n0 + n1)  { r = 1; j = i - n0; }
    else                   { r = 2; j = i - n0 - n1; }
    const int* d = (r == 0) ? d0 : (r == 1) ? d1 : d2;
    atomicAdd(&cnt[(size_t)r * N + d[j]], 1);
}

// block-local exclusive scan of cnt -> off, block totals -> bs
__global__ void scan1(const int* __restrict__ cnt, int* __restrict__ off,
                      int* __restrict__ bs, int N, int nchunks) {
    int r = blockIdx.y, c = blockIdx.x, tid = threadIdx.x;
    int i = c * SB + tid;
    __shared__ int s[SB];
    int v = (i < N) ? cnt[(size_t)r * N + i] : 0;
    s[tid] = v; __syncthreads();
    for (int d = 1; d < SB; d <<= 1) {
        int tv = (tid >= d) ? s[tid - d] : 0;
        __syncthreads();
        s[tid] += tv;
        __syncthreads();
    }
    if (i < N) off[(size_t)r * N + i] = s[tid] - v;     // exclusive within chunk
    if (tid == SB - 1) bs[r * nchunks + c] = s[tid];
}

// scan the chunk totals (nchunks <= 512)
__global__ void scan2(int* __restrict__ bs, int nchunks) {
    int r = blockIdx.x, tid = threadIdx.x;
    __shared__ int s[512];
    int v = (tid < nchunks) ? bs[r * nchunks + tid] : 0;
    s[tid] = v; __syncthreads();
    for (int d = 1; d < 512; d <<= 1) {
        int tv = (tid >= d) ? s[tid - d] : 0;
        __syncthreads();
        s[tid] += tv;
        __syncthreads();
    }
    if (tid < nchunks) bs[r * nchunks + tid] = s[tid] - v;  // exclusive
}

// add chunk offsets, produce final exclusive offsets + cursor copy
__global__ void scan3(int* __restrict__ off, const int* __restrict__ bs,
                      int* __restrict__ cur, int N, int nchunks) {
    int r = blockIdx.y;
    int i = blockIdx.x * SB + threadIdx.x;
    if (i < N) {
        int v = off[(size_t)r * N + i] + bs[r * nchunks + blockIdx.x];
        off[(size_t)r * N + i] = v;
        cur[(size_t)r * N + i] = v;
    }
}

// bucket-fill edge ids sorted by destination, all 3 relations in one launch
__global__ void fill_all(const int* __restrict__ d0, const int* __restrict__ d1,
                         const int* __restrict__ d2, int* __restrict__ cur,
                         int* __restrict__ eid, int N, int n0, int n1, int n2) {
    int i = blockIdx.x * blockDim.x + threadIdx.x;
    int total = n0 + n1 + n2;
    if (i >= total) return;
    int r, j, base;
    if (i < n0)            { r = 0; j = i;            base = 0; }
    else if (i < n0 + n1)  { r = 1; j = i - n0;       base = n0; }
    else                   { r = 2; j = i - n0 - n1;  base = n0 + n1; }
    const int* d = (r == 0) ? d0 : (r == 1) ? d1 : d2;
    int node = d[j];
    int p = atomicAdd(&cur[(size_t)r * N + node], 1);
    eid[base + p] = j;
}

// ---------------------------------------------------------------------------
// Fused: gather-mean (CSR) + tanh-gate attention + projection.
// 256 threads = 8 nodes x 32 threads, wave-local groups (no __syncthreads).
// Gather main loop: unconditional batches of 8 (8 eids then 8 independent
// row loads in flight), then a 4-batch and scalar tail. No predication in
// unrolled bodies (R5 lesson: predicated slots ballooned VGPR 52->196).
// ---------------------------------------------------------------------------
__global__ __launch_bounds__(256) void node_fused(
        const float* __restrict__ E0, const float* __restrict__ E1,
        const float* __restrict__ E2,
        const int* __restrict__ eid,   // [sum nE], per-relation bases
        const int* __restrict__ off,   // [3,N]
        const int* __restrict__ cnt,   // [3,N]
        const float* __restrict__ W1, const float* __restrict__ W2,
        const float* __restrict__ W3,
        float* __restrict__ out, int N, int base1, int base2) {
    const int ln = threadIdx.x >> 5;     // local node 0..7
    const int t  = threadIdx.x & 31;     // lane in group
    const int node = blockIdx.x * NPB + ln;
    if (node >= N) return;

    __shared__ float Ysh[NPB][3][DE];    // 12 KB
    __shared__ float OYsh[NPB][DE];      // 4 KB

    const float* Es[3] = { E0, E1, E2 };
    const int ebase[3] = { 0, base1, base2 };

    // ---- gather + mean: thread t owns cols 4t..4t+3 (f4 per edge row)
    #pragma unroll
    for (int r = 0; r < 3; ++r) {
        int start = off[(size_t)r * N + node];
        int deg   = cnt[(size_t)r * N + node];
        const int* el = eid + ebase[r] + start;
        const float* E = Es[r];
        f4 acc = {0.f, 0.f, 0.f, 0.f};

        int k = 0;
        for (; k + 8 <= deg; k += 8) {
            int e0 = el[k + 0], e1 = el[k + 1], e2 = el[k + 2], e3 = el[k + 3];
            int e4 = el[k + 4], e5 = el[k + 5], e6 = el[k + 6], e7 = el[k + 7];
            f4 v0 = __builtin_nontemporal_load(
                reinterpret_cast<const f4*>(E + (size_t)e0 * DE + t * 4));
            f4 v1 = __builtin_nontemporal_load(
                reinterpret_cast<const f4*>(E + (size_t)e1 * DE + t * 4));
            f4 v2 = __builtin_nontemporal_load(
                reinterpret_cast<const f4*>(E + (size_t)e2 * DE + t * 4));
            f4 v3 = __builtin_nontemporal_load(
                reinterpret_cast<const f4*>(E + (size_t)e3 * DE + t * 4));
            f4 v4 = __builtin_nontemporal_load(
                reinterpret_cast<const f4*>(E + (size_t)e4 * DE + t * 4));
            f4 v5 = __builtin_nontemporal_load(
                reinterpret_cast<const f4*>(E + (size_t)e5 * DE + t * 4));
            f4 v6 = __builtin_nontemporal_load(
                reinterpret_cast<const f4*>(E + (size_t)e6 * DE + t * 4));
            f4 v7 = __builtin_nontemporal_load(
                reinterpret_cast<const f4*>(E + (size_t)e7 * DE + t * 4));
            acc += ((v0 + v1) + (v2 + v3)) + ((v4 + v5) + (v6 + v7));
        }
        if (k + 4 <= deg) {
            int e0 = el[k + 0], e1 = el[k + 1], e2 = el[k + 2], e3 = el[k + 3];
            f4 v0 = __builtin_nontemporal_load(
                reinterpret_cast<const f4*>(E + (size_t)e0 * DE + t * 4));
            f4 v1 = __builtin_nontemporal_load(
                reinterpret_cast<const f4*>(E + (size_t)e1 * DE + t * 4));
            f4 v2 = __builtin_nontemporal_load(
                reinterpret_cast<const f4*>(E + (size_t)e2 * DE + t * 4));
            f4 v3 = __builtin_nontemporal_load(
                reinterpret_cast<const f4*>(E + (size_t)e3 * DE + t * 4));
            acc += (v0 + v1) + (v2 + v3);
            k += 4;
        }
        for (; k < deg; ++k) {
            int e = el[k];
            f4 v = __builtin_nontemporal_load(
                reinterpret_cast<const f4*>(E + (size_t)e * DE + t * 4));
            acc += v;
        }

        float inv = 1.0f / fmaxf((float)deg, 1.0f);
        acc *= inv;
        *reinterpret_cast<f4*>(&Ysh[ln][r][t * 4]) = acc;
    }

    // ---- z[r][j] = sum_d Y[r][d] * W1[d][t + 32j]   (register-blocked)
    float z[3][4] = {{0,0,0,0},{0,0,0,0},{0,0,0,0}};
    for (int d0 = 0; d0 < DE; d0 += 4) {
        f4 y0 = *reinterpret_cast<const f4*>(&Ysh[ln][0][d0]);
        f4 y1 = *reinterpret_cast<const f4*>(&Ysh[ln][1][d0]);
        f4 y2 = *reinterpret_cast<const f4*>(&Ysh[ln][2][d0]);
        #pragma unroll
        for (int dd = 0; dd < 4; ++dd) {
            int d = d0 + dd;
            const float* wrow = W1 + (size_t)d * DE + t;
            float w0 = wrow[0], w1 = wrow[32], w2 = wrow[64], w3 = wrow[96];
            float a0 = y0[dd], a1 = y1[dd], a2 = y2[dd];
            z[0][0] = fmaf(a0, w0, z[0][0]); z[0][1] = fmaf(a0, w1, z[0][1]);
            z[0][2] = fmaf(a0, w2, z[0][2]); z[0][3] = fmaf(a0, w3, z[0][3]);
            z[1][0] = fmaf(a1, w0, z[1][0]); z[1][1] = fmaf(a1, w1, z[1][1]);
            z[1][2] = fmaf(a1, w2, z[1][2]); z[1][3] = fmaf(a1, w3, z[1][3]);
            z[2][0] = fmaf(a2, w0, z[2][0]); z[2][1] = fmaf(a2, w1, z[2][1]);
            z[2][2] = fmaf(a2, w2, z[2][2]); z[2][3] = fmaf(a2, w3, z[2][3]);
        }
    }

    // ---- scores: e_r = sum_o tanh(z_r[o]) * W2[o]; reduce over 32 lanes
    float s0 = 0.f, s1 = 0.f, s2 = 0.f;
    #pragma unroll
    for (int j = 0; j < 4; ++j) {
        float w2v = W2[t + j * 32];
        s0 = fmaf(tanhf(z[0][j]), w2v, s0);
        s1 = fmaf(tanhf(z[1][j]), w2v, s1);
        s2 = fmaf(tanhf(z[2][j]), w2v, s2);
    }
    #pragma unroll
    for (int m = 16; m >= 1; m >>= 1) {
        s0 += __shfl_xor(s0, m);
        s1 += __shfl_xor(s1, m);
        s2 += __shfl_xor(s2, m);
    }
    float mx = fmaxf(s0, fmaxf(s1, s2));
    float x0 = __expf(s0 - mx), x1 = __expf(s1 - mx), x2 = __expf(s2 - mx);
    float inv = 1.0f / (x0 + x1 + x2);
    float a0 = x0 * inv, a1 = x1 * inv, a2 = x2 * inv;

    // ---- OY = sum_r a_r * Y_r  -> LDS
    #pragma unroll
    for (int j = 0; j < 4; ++j) {
        int o = t + j * 32;
        OYsh[ln][o] = a0 * Ysh[ln][0][o] + a1 * Ysh[ln][1][o] + a2 * Ysh[ln][2][o];
    }

    // ---- out = OY @ W3 (register-blocked, 4 cols/thread)
    float o4[4] = {0, 0, 0, 0};
    for (int d0 = 0; d0 < DE; d0 += 4) {
        f4 oy = *reinterpret_cast<const f4*>(&OYsh[ln][d0]);
        #pragma unroll
        for (int dd = 0; dd < 4; ++dd) {
            int d = d0 + dd;
            const float* wrow = W3 + (size_t)d * DE + t;
            o4[0] = fmaf(oy[dd], wrow[0],  o4[0]);
            o4[1] = fmaf(oy[dd], wrow[32], o4[1]);
            o4[2] = fmaf(oy[dd], wrow[64], o4[2]);
            o4[3] = fmaf(oy[dd], wrow[96], o4[3]);
        }
    }
    #pragma unroll
    for (int j = 0; j < 4; ++j) out[(size_t)node * DE + t + j * 32] = o4[j];
}

// ---------------------------------------------------------------------------
// launch
// ---------------------------------------------------------------------------
extern "C" void kernel_launch(void* const* d_in, const int* in_sizes, int n_in,
                              void* d_out, int out_size, void* d_ws, size_t ws_size,
                              hipStream_t stream) {
    const float* E_C = (const float*)d_in[0];
    const float* E_D = (const float*)d_in[1];
    const float* E_M = (const float*)d_in[2];
    const int* dst_C = (const int*)d_in[3];
    const int* dst_D = (const int*)d_in[4];
    const int* dst_M = (const int*)d_in[5];
    const float* W1 = (const float*)d_in[7];
    const float* W2 = (const float*)d_in[8];
    const float* W3 = (const float*)d_in[9];
    float* out = (float*)d_out;

    const int N = out_size / DE;                     // 100000
    const int nE[3] = { in_sizes[3], in_sizes[4], in_sizes[5] };
    const int NEtot = nE[0] + nE[1] + nE[2];
    const int nchunks = (N + SB - 1) / SB;           // 391 for N=100000

    // workspace (ints): eid[NEtot] | cnt[3N] | off[3N] | cur[3N] | bs[3*nchunks]
    int* eid = (int*)d_ws;
    int* cnt = eid + NEtot;
    int* off = cnt + 3 * (size_t)N;
    int* cur = off + 3 * (size_t)N;
    int* bs  = cur + 3 * (size_t)N;

    (void)hipMemsetAsync(cnt, 0, 3 * (size_t)N * sizeof(int), stream);

    {
        int blocks = (NEtot + 255) / 256;
        count_all<<<blocks, 256, 0, stream>>>(dst_C, dst_D, dst_M, cnt,
                                              N, nE[0], nE[1], nE[2]);
    }

    dim3 g1(nchunks, 3);
    scan1<<<g1, SB, 0, stream>>>(cnt, off, bs, N, nchunks);
    scan2<<<3, 512, 0, stream>>>(bs, nchunks);
    scan3<<<g1, SB, 0, stream>>>(off, bs, cur, N, nchunks);

    {
        int blocks = (NEtot + 255) / 256;
        fill_all<<<blocks, 256, 0, stream>>>(dst_C, dst_D, dst_M, cur, eid,
                                             N, nE[0], nE[1], nE[2]);
    }

    int nblocks = (N + NPB - 1) / NPB;
    node_fused<<<nblocks, 256, 0, stream>>>(
        E_C, E_D, E_M, eid, off, cnt, W1, W2, W3, out,
        N, nE[0], nE[0] + nE[1]);
}

// Round 7
// 986.622 us; speedup vs baseline: 2.7110x; 1.0066x over previous
//
#include <hip/hip_runtime.h>
#include <hip/hip_bf16.h>

#define DE 128
#define SB 256          // scan chunk
#define NPB 8           // nodes per block in fused kernel (8 * 32 threads = 256)

typedef float f4 __attribute__((ext_vector_type(4)));

// ---------------------------------------------------------------------------
// CSR build: histogram over all 3 relations in one launch
// ---------------------------------------------------------------------------
__global__ void count_all(const int* __restrict__ d0, const int* __restrict__ d1,
                          const int* __restrict__ d2, int* __restrict__ cnt,
                          int N, int n0, int n1, int n2) {
    int i = blockIdx.x * blockDim.x + threadIdx.x;
    int total = n0 + n1 + n2;
    if (i >= total) return;
    int r, j;
    if (i < n0)            { r = 0; j = i; }
    else if (i < n0 + n1)  { r = 1; j = i - n0; }
    else                   { r = 2; j = i - n0 - n1; }
    const int* d = (r == 0) ? d0 : (r == 1) ? d1 : d2;
    atomicAdd(&cnt[(size_t)r * N + d[j]], 1);
}

// block-local exclusive scan of cnt -> off, block totals -> bs
__global__ void scan1(const int* __restrict__ cnt, int* __restrict__ off,
                      int* __restrict__ bs, int N, int nchunks) {
    int r = blockIdx.y, c = blockIdx.x, tid = threadIdx.x;
    int i = c * SB + tid;
    __shared__ int s[SB];
    int v = (i < N) ? cnt[(size_t)r * N + i] : 0;
    s[tid] = v; __syncthreads();
    for (int d = 1; d < SB; d <<= 1) {
        int tv = (tid >= d) ? s[tid - d] : 0;
        __syncthreads();
        s[tid] += tv;
        __syncthreads();
    }
    if (i < N) off[(size_t)r * N + i] = s[tid] - v;     // exclusive within chunk
    if (tid == SB - 1) bs[r * nchunks + c] = s[tid];
}

// scan the chunk totals (nchunks <= 512)
__global__ void scan2(int* __restrict__ bs, int nchunks) {
    int r = blockIdx.x, tid = threadIdx.x;
    __shared__ int s[512];
    int v = (tid < nchunks) ? bs[r * nchunks + tid] : 0;
    s[tid] = v; __syncthreads();
    for (int d = 1; d < 512; d <<= 1) {
        int tv = (tid >= d) ? s[tid - d] : 0;
        __syncthreads();
        s[tid] += tv;
        __syncthreads();
    }
    if (tid < nchunks) bs[r * nchunks + tid] = s[tid] - v;  // exclusive
}

// add chunk offsets, produce final exclusive offsets + cursor copy
__global__ void scan3(int* __restrict__ off, const int* __restrict__ bs,
                      int* __restrict__ cur, int N, int nchunks) {
    int r = blockIdx.y;
    int i = blockIdx.x * SB + threadIdx.x;
    if (i < N) {
        int v = off[(size_t)r * N + i] + bs[r * nchunks + blockIdx.x];
        off[(size_t)r * N + i] = v;
        cur[(size_t)r * N + i] = v;
    }
}

// bucket-fill edge ids sorted by destination, all 3 relations in one launch
__global__ void fill_all(const int* __restrict__ d0, const int* __restrict__ d1,
                         const int* __restrict__ d2, int* __restrict__ cur,
                         int* __restrict__ eid, int N, int n0, int n1, int n2) {
    int i = blockIdx.x * blockDim.x + threadIdx.x;
    int total = n0 + n1 + n2;
    if (i >= total) return;
    int r, j, base;
    if (i < n0)            { r = 0; j = i;            base = 0; }
    else if (i < n0 + n1)  { r = 1; j = i - n0;       base = n0; }
    else                   { r = 2; j = i - n0 - n1;  base = n0 + n1; }
    const int* d = (r == 0) ? d0 : (r == 1) ? d1 : d2;
    int node = d[j];
    int p = atomicAdd(&cur[(size_t)r * N + node], 1);
    eid[base + p] = j;
}

// ---------------------------------------------------------------------------
// Fused: gather-mean (CSR) + tanh-gate attention + projection.
// 256 threads = 8 nodes x 32 threads, wave-local groups (no __syncthreads).
// MLP blocking: thread t owns CONSECUTIVE output cols 4t..4t+3 so each
// weight fetch is one coalesced f4 load (1024 scalar vmem -> 256 f4 vmem
// per thread vs R6).
// ---------------------------------------------------------------------------
__global__ __launch_bounds__(256) void node_fused(
        const float* __restrict__ E0, const float* __restrict__ E1,
        const float* __restrict__ E2,
        const int* __restrict__ eid,   // [sum nE], per-relation bases
        const int* __restrict__ off,   // [3,N]
        const int* __restrict__ cnt,   // [3,N]
        const float* __restrict__ W1, const float* __restrict__ W2,
        const float* __restrict__ W3,
        float* __restrict__ out, int N, int base1, int base2) {
    const int ln = threadIdx.x >> 5;     // local node 0..7
    const int t  = threadIdx.x & 31;     // lane in group
    const int node = blockIdx.x * NPB + ln;
    if (node >= N) return;

    __shared__ float Ysh[NPB][3][DE];    // 12 KB
    __shared__ float OYsh[NPB][DE];      // 4 KB

    const float* Es[3] = { E0, E1, E2 };
    const int ebase[3] = { 0, base1, base2 };

    // ---- gather + mean: thread t owns cols 4t..4t+3 (f4 per edge row)
    #pragma unroll
    for (int r = 0; r < 3; ++r) {
        int start = off[(size_t)r * N + node];
        int deg   = cnt[(size_t)r * N + node];
        const int* el = eid + ebase[r] + start;
        const float* E = Es[r];
        f4 acc = {0.f, 0.f, 0.f, 0.f};

        int k = 0;
        for (; k + 8 <= deg; k += 8) {
            int e0 = el[k + 0], e1 = el[k + 1], e2 = el[k + 2], e3 = el[k + 3];
            int e4 = el[k + 4], e5 = el[k + 5], e6 = el[k + 6], e7 = el[k + 7];
            f4 v0 = __builtin_nontemporal_load(
                reinterpret_cast<const f4*>(E + (size_t)e0 * DE + t * 4));
            f4 v1 = __builtin_nontemporal_load(
                reinterpret_cast<const f4*>(E + (size_t)e1 * DE + t * 4));
            f4 v2 = __builtin_nontemporal_load(
                reinterpret_cast<const f4*>(E + (size_t)e2 * DE + t * 4));
            f4 v3 = __builtin_nontemporal_load(
                reinterpret_cast<const f4*>(E + (size_t)e3 * DE + t * 4));
            f4 v4 = __builtin_nontemporal_load(
                reinterpret_cast<const f4*>(E + (size_t)e4 * DE + t * 4));
            f4 v5 = __builtin_nontemporal_load(
                reinterpret_cast<const f4*>(E + (size_t)e5 * DE + t * 4));
            f4 v6 = __builtin_nontemporal_load(
                reinterpret_cast<const f4*>(E + (size_t)e6 * DE + t * 4));
            f4 v7 = __builtin_nontemporal_load(
                reinterpret_cast<const f4*>(E + (size_t)e7 * DE + t * 4));
            acc += ((v0 + v1) + (v2 + v3)) + ((v4 + v5) + (v6 + v7));
        }
        if (k + 4 <= deg) {
            int e0 = el[k + 0], e1 = el[k + 1], e2 = el[k + 2], e3 = el[k + 3];
            f4 v0 = __builtin_nontemporal_load(
                reinterpret_cast<const f4*>(E + (size_t)e0 * DE + t * 4));
            f4 v1 = __builtin_nontemporal_load(
                reinterpret_cast<const f4*>(E + (size_t)e1 * DE + t * 4));
            f4 v2 = __builtin_nontemporal_load(
                reinterpret_cast<const f4*>(E + (size_t)e2 * DE + t * 4));
            f4 v3 = __builtin_nontemporal_load(
                reinterpret_cast<const f4*>(E + (size_t)e3 * DE + t * 4));
            acc += (v0 + v1) + (v2 + v3);
            k += 4;
        }
        for (; k < deg; ++k) {
            int e = el[k];
            f4 v = __builtin_nontemporal_load(
                reinterpret_cast<const f4*>(E + (size_t)e * DE + t * 4));
            acc += v;
        }

        float inv = 1.0f / fmaxf((float)deg, 1.0f);
        acc *= inv;
        *reinterpret_cast<f4*>(&Ysh[ln][r][t * 4]) = acc;
    }

    // ---- z[r][j] = sum_d Y[r][d] * W1[d][4t+j]   (consecutive f4 blocking)
    float z[3][4] = {{0,0,0,0},{0,0,0,0},{0,0,0,0}};
    for (int d0 = 0; d0 < DE; d0 += 4) {
        f4 y0 = *reinterpret_cast<const f4*>(&Ysh[ln][0][d0]);
        f4 y1 = *reinterpret_cast<const f4*>(&Ysh[ln][1][d0]);
        f4 y2 = *reinterpret_cast<const f4*>(&Ysh[ln][2][d0]);
        #pragma unroll
        for (int dd = 0; dd < 4; ++dd) {
            int d = d0 + dd;
            f4 w = *reinterpret_cast<const f4*>(W1 + (size_t)d * DE + t * 4);
            float a0 = y0[dd], a1 = y1[dd], a2 = y2[dd];
            #pragma unroll
            for (int j = 0; j < 4; ++j) {
                z[0][j] = fmaf(a0, w[j], z[0][j]);
                z[1][j] = fmaf(a1, w[j], z[1][j]);
                z[2][j] = fmaf(a2, w[j], z[2][j]);
            }
        }
    }

    // ---- scores: e_r = sum_o tanh(z_r[o]) * W2[o]; reduce over 32 lanes
    f4 w2v = *reinterpret_cast<const f4*>(W2 + t * 4);
    float s0 = 0.f, s1 = 0.f, s2 = 0.f;
    #pragma unroll
    for (int j = 0; j < 4; ++j) {
        s0 = fmaf(tanhf(z[0][j]), w2v[j], s0);
        s1 = fmaf(tanhf(z[1][j]), w2v[j], s1);
        s2 = fmaf(tanhf(z[2][j]), w2v[j], s2);
    }
    #pragma unroll
    for (int m = 16; m >= 1; m >>= 1) {
        s0 += __shfl_xor(s0, m);
        s1 += __shfl_xor(s1, m);
        s2 += __shfl_xor(s2, m);
    }
    float mx = fmaxf(s0, fmaxf(s1, s2));
    float x0 = __expf(s0 - mx), x1 = __expf(s1 - mx), x2 = __expf(s2 - mx);
    float inv = 1.0f / (x0 + x1 + x2);
    float a0 = x0 * inv, a1 = x1 * inv, a2 = x2 * inv;

    // ---- OY = sum_r a_r * Y_r  -> LDS (f4 store, cols 4t..4t+3)
    {
        f4 y0 = *reinterpret_cast<const f4*>(&Ysh[ln][0][t * 4]);
        f4 y1 = *reinterpret_cast<const f4*>(&Ysh[ln][1][t * 4]);
        f4 y2 = *reinterpret_cast<const f4*>(&Ysh[ln][2][t * 4]);
        f4 oy = a0 * y0 + a1 * y1 + a2 * y2;
        *reinterpret_cast<f4*>(&OYsh[ln][t * 4]) = oy;
    }

    // ---- out = OY @ W3 (consecutive f4 blocking)
    f4 o4 = {0.f, 0.f, 0.f, 0.f};
    for (int d0 = 0; d0 < DE; d0 += 4) {
        f4 oy = *reinterpret_cast<const f4*>(&OYsh[ln][d0]);
        #pragma unroll
        for (int dd = 0; dd < 4; ++dd) {
            int d = d0 + dd;
            f4 w = *reinterpret_cast<const f4*>(W3 + (size_t)d * DE + t * 4);
            #pragma unroll
            for (int j = 0; j < 4; ++j) o4[j] = fmaf(oy[dd], w[j], o4[j]);
        }
    }
    *reinterpret_cast<f4*>(out + (size_t)node * DE + t * 4) = o4;
}

// ---------------------------------------------------------------------------
// launch
// ---------------------------------------------------------------------------
extern "C" void kernel_launch(void* const* d_in, const int* in_sizes, int n_in,
                              void* d_out, int out_size, void* d_ws, size_t ws_size,
                              hipStream_t stream) {
    const float* E_C = (const float*)d_in[0];
    const float* E_D = (const float*)d_in[1];
    const float* E_M = (const float*)d_in[2];
    const int* dst_C = (const int*)d_in[3];
    const int* dst_D = (const int*)d_in[4];
    const int* dst_M = (const int*)d_in[5];
    const float* W1 = (const float*)d_in[7];
    const float* W2 = (const float*)d_in[8];
    const float* W3 = (const float*)d_in[9];
    float* out = (float*)d_out;

    const int N = out_size / DE;                     // 100000
    const int nE[3] = { in_sizes[3], in_sizes[4], in_sizes[5] };
    const int NEtot = nE[0] + nE[1] + nE[2];
    const int nchunks = (N + SB - 1) / SB;           // 391 for N=100000

    // workspace (ints): eid[NEtot] | cnt[3N] | off[3N] | cur[3N] | bs[3*nchunks]
    int* eid = (int*)d_ws;
    int* cnt = eid + NEtot;
    int* off = cnt + 3 * (size_t)N;
    int* cur = off + 3 * (size_t)N;
    int* bs  = cur + 3 * (size_t)N;

    (void)hipMemsetAsync(cnt, 0, 3 * (size_t)N * sizeof(int), stream);

    {
        int blocks = (NEtot + 255) / 256;
        count_all<<<blocks, 256, 0, stream>>>(dst_C, dst_D, dst_M, cnt,
                                              N, nE[0], nE[1], nE[2]);
    }

    dim3 g1(nchunks, 3);
    scan1<<<g1, SB, 0, stream>>>(cnt, off, bs, N, nchunks);
    scan2<<<3, 512, 0, stream>>>(bs, nchunks);
    scan3<<<g1, SB, 0, stream>>>(off, bs, cur, N, nchunks);

    {
        int blocks = (NEtot + 255) / 256;
        fill_all<<<blocks, 256, 0, stream>>>(dst_C, dst_D, dst_M, cur, eid,
                                             N, nE[0], nE[1], nE[2]);
    }

    int nblocks = (N + NPB - 1) / NPB;
    node_fused<<<nblocks, 256, 0, stream>>>(
        E_C, E_D, E_M, eid, off, cnt, W1, W2, W3, out,
        N, nE[0], nE[0] + nE[1]);
}